// Round 17
// baseline (171.609 us; speedup 1.0000x reference)
//
#include <hip/hip_runtime.h>
#include <stdint.h>

#define N_NODES 8192

typedef __attribute__((ext_vector_type(8))) short bhalf8;
typedef __attribute__((ext_vector_type(16))) float f32x16;
typedef __attribute__((ext_vector_type(4))) float f32x4;

__device__ inline unsigned short f2bf_rne(float f) {
    unsigned u = __builtin_bit_cast(unsigned, f);
    u += 0x7FFFu + ((u >> 16) & 1u);
    return (unsigned short)(u >> 16);
}

__device__ inline float bf2f(unsigned short s) {
    unsigned u = ((unsigned)s) << 16;
    return __builtin_bit_cast(float, u);
}

__device__ inline bhalf8 mk8(unsigned a, unsigned b, unsigned c, unsigned d) {
    union { unsigned u[4]; bhalf8 v; } U;
    U.u[0] = a; U.u[1] = b; U.u[2] = c; U.u[3] = d;
    return U.v;
}

// v_permlane32_swap_b32 a, b:  a = {a_lo, b_lo}, b = {a_hi, b_hi}  (rows = 32-lane halves)
__device__ inline void pl32swap(unsigned& a, unsigned& b) {
    asm("v_permlane32_swap_b32 %0, %1" : "+v"(a), "+v"(b));
}

// ---------------- k1: projections straight from f32 inputs (weights read transposed,
// coalesced, directly from global).
// fi pre-scaled by -log2e (feeds only QK^T; scores arrive exp2-ready).
// fjF layout: chunk c (64 j) x k-chunk kc (8 k) x 64 j-rows x 16 B:
//   ushort idx = (j>>6)*8192 + (k>>3)*512 + (j&63)*8 + (k&7)
// fkF layout: chunk c x j-slice s (8 j) x 128 d-rows x 16 B:
//   ushort idx = (j>>6)*8192 + ((j>>3)&7)*1024 + d*8 + (j&7)
__global__ __launch_bounds__(256) void k_proj(const float* __restrict__ landmarks,
                                              const float* __restrict__ features,
                                              const float* __restrict__ Wi,
                                              const float* __restrict__ bi,
                                              const float* __restrict__ Wj,
                                              const float* __restrict__ bj,
                                              const float* __restrict__ Wk,
                                              const float* __restrict__ bk,
                                              unsigned short* __restrict__ fi,
                                              unsigned short* __restrict__ fjF,
                                              unsigned short* __restrict__ fkF) {
    const int tid = threadIdx.x, w = tid >> 6, l = tid & 63, h = l >> 5, ln = l & 31;
    const unsigned bid = blockIdx.x;
    const int it = bid / 3, ng = bid - it * 3;
    const int i0 = it * 32;
    const int d = w * 32 + ln;
    const int row = i0 + ln;
    const float* Wsel = (ng == 0) ? Wi : ((ng == 1) ? Wj : Wk);
    const float* bsel = (ng == 0) ? bi : ((ng == 1) ? bj : bk);
    f32x16 acc = {};
#pragma unroll
    for (int s = 0; s < 17; ++s) {
        union { unsigned short us[8]; bhalf8 v; } A;
        union { unsigned short us[8]; bhalf8 v; } B;
        if (s < 16) {
            const float* fp = features + (size_t)row * 256 + s * 16 + h * 8;
            f32x4 v0 = *(const f32x4*)(fp);
            f32x4 v1 = *(const f32x4*)(fp + 4);
#pragma unroll
            for (int e = 0; e < 4; ++e) { A.us[e] = f2bf_rne(v0[e]); A.us[4 + e] = f2bf_rne(v1[e]); }
            // B: W rows (kk+3) for kk = s*16 + h*8 + e; coalesced across lanes (d varies)
#pragma unroll
            for (int e = 0; e < 8; ++e)
                B.us[e] = f2bf_rne(Wsel[(size_t)(s * 16 + h * 8 + e + 3) * 128 + d]);
        } else {
#pragma unroll
            for (int e = 0; e < 8; ++e) { A.us[e] = 0; B.us[e] = 0; }
            if (h == 0) {
                A.us[0] = f2bf_rne(landmarks[row * 3 + 0]);
                A.us[1] = f2bf_rne(landmarks[row * 3 + 1]);
                A.us[2] = f2bf_rne(landmarks[row * 3 + 2]);
                B.us[0] = f2bf_rne(Wsel[(size_t)0 * 128 + d]);
                B.us[1] = f2bf_rne(Wsel[(size_t)1 * 128 + d]);
                B.us[2] = f2bf_rne(Wsel[(size_t)2 * 128 + d]);
            }
        }
        acc = __builtin_amdgcn_mfma_f32_32x32x16_bf16(A.v, B.v, acc, 0, 0, 0);
    }
    const float bias = bsel[d];
    if (ng == 0) {
#pragma unroll
        for (int q = 0; q < 4; ++q) {
            int ib = i0 + 8 * q + 4 * h;
#pragma unroll
            for (int r = 0; r < 4; ++r)
                fi[(size_t)(ib + r) * 128 + d] =
                    f2bf_rne((acc[4 * q + r] + bias) * -1.44269504f);
        }
    } else if (ng == 1) {
#pragma unroll
        for (int q = 0; q < 4; ++q) {
            int ib = i0 + 8 * q + 4 * h;
#pragma unroll
            for (int r = 0; r < 4; ++r) {
                int j = ib + r;
                fjF[(size_t)(j >> 6) * 8192 + (d >> 3) * 512 + (j & 63) * 8 + (d & 7)] =
                    f2bf_rne(acc[4 * q + r] + bias);
            }
        }
    } else {
#pragma unroll
        for (int q = 0; q < 4; ++q) {
            int ib = i0 + 8 * q + 4 * h;
            ushort4 pk;
            pk.x = f2bf_rne(acc[4 * q + 0] + bias);
            pk.y = f2bf_rne(acc[4 * q + 1] + bias);
            pk.z = f2bf_rne(acc[4 * q + 2] + bias);
            pk.w = f2bf_rne(acc[4 * q + 3] + bias);
            *(ushort4*)(fkF + (size_t)(ib >> 6) * 8192 + ((ib >> 3) & 7) * 1024 + d * 8 + 4 * h) = pk;
        }
    }
}

// ---------------- k2: barrier-free streaming, d-split occupancy probe ----------
// Grid 1024 = 4 jq x 128 rt x 2 dh. Each block: full QK+SIG over its 32 chunks, PV only
// its 64-d half -> acc[2] = 32 AGPR; total regs ~132 (<170 = 3-wave boundary). If the HW
// register granule is fine (m68), 3 waves/SIMD materialize WITHOUT launch_bounds squeeze
// (R8/R10's failure mode). QK+SIG duplicated x2 is the price; stall-dominated loop
// (issue ~38% of wall) should net-win from +50% latency hiding.
__global__ __launch_bounds__(256, 2) void k_attn(const unsigned short* __restrict__ fi,
                                                 const unsigned short* __restrict__ fjF,
                                                 const unsigned short* __restrict__ fkF,
                                                 unsigned short* __restrict__ num_bf,
                                                 float* __restrict__ den_part) {
    __shared__ __align__(16) char smem[18432];   // 17,408 B reduce buf + 512 B denb

    const int tid = threadIdx.x;
    const int w = tid >> 6, l = tid & 63, h = l >> 5, ln = l & 31;
    const int ih = w >> 1, jh = w & 1;
    const unsigned b = blockIdx.x;             // 1024 blocks; xcd = b & 7 (round-robin)
    const int xcd = b & 7;
    const int jq = xcd >> 1;                   // one jq per XCD-pair (L2 locality, R4-proven)
    const int dh = (int)((b >> 3) & 1);        // d-half this block accumulates
    const int rt = (int)(b >> 4) + ((xcd & 1) << 6);
    const int i0 = rt * 64;

    // hoist fi B-fragments for this wave's 32-i block (32 VGPRs), reused across all j
    bhalf8 bfi[8];
#pragma unroll
    for (int s = 0; s < 8; ++s)
        bfi[s] = *(const bhalf8*)(fi + (size_t)(i0 + ih * 32 + ln) * 128 + s * 16 + h * 8);

    f32x16 acc[2] = {};   // numT partials: [d-tile 0..1 within dh-half][wave's 32 i]
    float da[4] = {};     // denom partial accumulators (8-deep chains)

    // per-lane fragment base pointers (ushort units); chunk stride = 8192 ushorts (16 KB)
    const unsigned short* fjp = fjF + (size_t)(jq * 32) * 8192 + (jh * 32 + ln) * 8 + h * 512;
    const unsigned short* fkp = fkF + (size_t)(jq * 32) * 8192 + (jh * 4 + h) * 1024
                                + dh * 512 + ln * 8;

    bhalf8 fjc[8];          // QK A-fragments of current chunk
    bhalf8 fkA[2], fkB[2];  // PV fk fragments (dh-half only)

    auto LOADFJ = [&](const unsigned short* p) {
#pragma unroll
        for (int ss = 0; ss < 4; ++ss) {
            fjc[2 * ss]     = *(const bhalf8*)(p + ss * 2048);
            fjc[2 * ss + 1] = *(const bhalf8*)(p + ss * 2048 + 1024);
        }
    };
    auto LOADFK = [&](const unsigned short* p) {
#pragma unroll
        for (int m4 = 0; m4 < 2; ++m4) {
            fkA[m4] = *(const bhalf8*)(p + m4 * 256);
            fkB[m4] = *(const bhalf8*)(p + 2048 + m4 * 256);
        }
    };

    LOADFJ(fjp);
    LOADFK(fkp);
#pragma unroll 1
    for (int mt = 0; mt < 32; ++mt) {
        // QK: scores arrive pre-scaled by -log2e (fi scaled at k1) — exp2-ready.
        f32x16 sa = {}, sb = {};
        __builtin_amdgcn_s_setprio(1);
#pragma unroll
        for (int ss = 0; ss < 4; ++ss) {
            sa = __builtin_amdgcn_mfma_f32_32x32x16_bf16(fjc[2 * ss], bfi[2 * ss], sa, 0, 0, 0);
            sb = __builtin_amdgcn_mfma_f32_32x32x16_bf16(fjc[2 * ss + 1], bfi[2 * ss + 1], sb, 0, 0, 0);
        }
        __builtin_amdgcn_s_setprio(0);
        fjp += 8192;
        LOADFJ(fjp);
        // sigmoid + denom + pack: x = rcp(1 + exp2(s')) — 16 independent chains
        unsigned p[8];
#pragma unroll
        for (int q = 0; q < 8; ++q) {
            float x0 = __builtin_amdgcn_rcpf(1.f + __builtin_amdgcn_exp2f(sa[2 * q] + sb[2 * q]));
            float x1 = __builtin_amdgcn_rcpf(1.f + __builtin_amdgcn_exp2f(sa[2 * q + 1] + sb[2 * q + 1]));
            da[q & 3] += x0 + x1;
            p[q] = __builtin_amdgcn_perm(__builtin_bit_cast(unsigned, x1),
                                         __builtin_bit_cast(unsigned, x0), 0x07060302u);
        }
        unsigned w0 = p[0], w2 = p[2]; pl32swap(w0, w2);
        unsigned w1 = p[1], w3 = p[3]; pl32swap(w1, w3);
        bhalf8 fb0 = mk8(w0, w1, w2, w3);
        unsigned w4 = p[4], w6 = p[6]; pl32swap(w4, w6);
        unsigned w5 = p[5], w7 = p[7]; pl32swap(w5, w7);
        bhalf8 fb1 = mk8(w4, w5, w6, w7);
        // PV (dh-half): numT[d][i] += fk[d][j-slice] * P^T[j-slice][i]
        __builtin_amdgcn_s_setprio(1);
#pragma unroll
        for (int m4 = 0; m4 < 2; ++m4)
            acc[m4] = __builtin_amdgcn_mfma_f32_32x32x16_bf16(fkA[m4], fb0, acc[m4], 0, 0, 0);
#pragma unroll
        for (int m4 = 0; m4 < 2; ++m4)
            acc[m4] = __builtin_amdgcn_mfma_f32_32x32x16_bf16(fkB[m4], fb1, acc[m4], 0, 0, 0);
        __builtin_amdgcn_s_setprio(0);
        fkp += 8192;
        LOADFK(fkp);
    }

    // denom: combine partials, fold lane l <-> l^32 (h halves), stash per wave.
    // Both dh twins compute/write identical den values — benign same-value race.
    float dacc = (da[0] + da[1]) + (da[2] + da[3]);
    dacc += __shfl_xor(dacc, 32, 64);
    float* denb = (float*)(smem + 17408);   // 128 floats after the 17,408 B reduce buf
    if (h == 0) denb[w * 32 + ln] = dacc;

    // num reduce over jh: buf [64 i][64 d + pad 4] f32
    float* buf = (float*)smem;
    __syncthreads();   // first barrier (no LDS used before)
    if (jh == 0) {
#pragma unroll
        for (int m4 = 0; m4 < 2; ++m4)
#pragma unroll
            for (int q = 0; q < 4; ++q) {
                f32x4 v = {acc[m4][4 * q + 0], acc[m4][4 * q + 1],
                           acc[m4][4 * q + 2], acc[m4][4 * q + 3]};
                *(f32x4*)(buf + (ih * 32 + ln) * 68 + m4 * 32 + 8 * q + 4 * h) = v;
            }
    }
    __syncthreads();
    if (jh == 1) {
#pragma unroll
        for (int m4 = 0; m4 < 2; ++m4)
#pragma unroll
            for (int q = 0; q < 4; ++q) {
                float* p4 = buf + (ih * 32 + ln) * 68 + m4 * 32 + 8 * q + 4 * h;
                f32x4 old = *(f32x4*)p4;
                f32x4 v = {acc[m4][4 * q + 0], acc[m4][4 * q + 1],
                           acc[m4][4 * q + 2], acc[m4][4 * q + 3]};
                *(f32x4*)p4 = old + v;
            }
    }
    __syncthreads();
#pragma unroll
    for (int e = 0; e < 4; ++e) {
        int v = e * 256 + tid;                 // 1024 float4-groups = 64 i x 16
        int iloc = v >> 4, d4 = (v & 15) * 4;
        f32x4 s4 = *(const f32x4*)(buf + iloc * 68 + d4);
        ushort4 pk;
        pk.x = f2bf_rne(s4.x);
        pk.y = f2bf_rne(s4.y);
        pk.z = f2bf_rne(s4.z);
        pk.w = f2bf_rne(s4.w);
        *(ushort4*)(num_bf + ((size_t)jq * N_NODES + i0 + iloc) * 128 + dh * 64 + d4) = pk;
    }
    if (tid < 64) {
        den_part[(size_t)jq * N_NODES + i0 + tid] =
            denb[(tid >> 5) * 64 + (tid & 31)] + denb[(tid >> 5) * 64 + 32 + (tid & 31)];
    }
}

// ---------------- k3: t = (sum num)/(sum den); out = t @ Wr + br + features ----------------
// num partials read as bf16 (half the bytes), accumulated in f32; Wr streamed directly
// from global (coalesced, L2-cached).
__global__ __launch_bounds__(256) void k_out(const float* __restrict__ Wr,
                                             const float* __restrict__ br,
                                             const float* __restrict__ features,
                                             const unsigned short* __restrict__ num_bf,
                                             const float* __restrict__ den_part,
                                             float* __restrict__ out) {
    __shared__ __align__(16) char smem[8192];   // t tile [32 i][256 B] swizzled
    char* const tb = smem;
    const int tid = threadIdx.x, w = tid >> 6, l = tid & 63, h = l >> 5, ln = l & 31;
    const int i0 = blockIdx.x * 32;
    // combine num/den partials -> t tile (bf16)
    {
        int i = tid >> 3, dseg = (tid & 7) * 16;
        f32x4 s[4] = {};
        float ds = 0.f;
#pragma unroll
        for (int q = 0; q < 4; ++q) {
            const unsigned short* np = num_bf + ((size_t)(q * N_NODES + i0 + i)) * 128 + dseg;
            bhalf8 b0 = *(const bhalf8*)(np);
            bhalf8 b1 = *(const bhalf8*)(np + 8);
#pragma unroll
            for (int k = 0; k < 8; ++k)
                s[k >> 2][k & 3] += bf2f((unsigned short)b0[k]);
#pragma unroll
            for (int k = 0; k < 8; ++k)
                s[2 + (k >> 2)][k & 3] += bf2f((unsigned short)b1[k]);
            ds += den_part[(size_t)q * N_NODES + i0 + i];
        }
        float inv = 1.0f / ds;
#pragma unroll
        for (int cc = 0; cc < 2; ++cc) {
            union { unsigned u[4]; bhalf8 v; } U;
#pragma unroll
            for (int m = 0; m < 4; ++m) {
                int e0 = cc * 8 + 2 * m;
                unsigned lo = f2bf_rne(s[e0 >> 2][e0 & 3] * inv);
                unsigned hi = f2bf_rne(s[(e0 + 1) >> 2][(e0 + 1) & 3] * inv);
                U.u[m] = lo | (hi << 16);
            }
            int slot = ((tid & 7) * 2 + cc) ^ (i & 15);
            *(bhalf8*)(tb + i * 256 + slot * 16) = U.v;
        }
    }
    __syncthreads();
    f32x16 acc[2] = {};
    const int cc0 = w * 64 + ln;   // this lane's output column base (nt adds 32)
#pragma unroll
    for (int s = 0; s < 8; ++s) {
        int ca = (s * 2 + h) ^ (ln & 15);
        bhalf8 af = *(const bhalf8*)(tb + ln * 256 + ca * 16);
#pragma unroll
        for (int nt = 0; nt < 2; ++nt) {
            int cc = cc0 + nt * 32;
            union { unsigned short us[8]; bhalf8 v; } B;
#pragma unroll
            for (int e = 0; e < 8; ++e)
                B.us[e] = f2bf_rne(Wr[(size_t)((s * 2 + h) * 8 + e) * 256 + cc]);
            acc[nt] = __builtin_amdgcn_mfma_f32_32x32x16_bf16(af, B.v, acc[nt], 0, 0, 0);
        }
    }
#pragma unroll
    for (int nt = 0; nt < 2; ++nt) {
        int cc = cc0 + nt * 32;
        float bias = br[cc];
#pragma unroll
        for (int q = 0; q < 4; ++q) {
#pragma unroll
            for (int r = 0; r < 4; ++r) {
                int i = i0 + 8 * q + 4 * h + r;
                out[(size_t)i * 256 + cc] = acc[nt][4 * q + r] + bias + features[(size_t)i * 256 + cc];
            }
        }
    }
}

extern "C" void kernel_launch(void* const* d_in, const int* in_sizes, int n_in,
                              void* d_out, int out_size, void* d_ws, size_t ws_size,
                              hipStream_t stream) {
    const float* landmarks = (const float*)d_in[0];
    const float* features  = (const float*)d_in[1];
    const float* Wi = (const float*)d_in[2];
    const float* bi = (const float*)d_in[3];
    const float* Wj = (const float*)d_in[4];
    const float* bj = (const float*)d_in[5];
    const float* Wk = (const float*)d_in[6];
    const float* bk = (const float*)d_in[7];
    const float* Wr = (const float*)d_in[8];
    const float* br = (const float*)d_in[9];

    char* ws = (char*)d_ws;
    unsigned short* fi      = (unsigned short*)(ws + 0);         // 8192x128 bf16   (2,097,152 B)
    unsigned short* fjF     = (unsigned short*)(ws + 2097152);   // fragment-major  (2,097,152 B)
    unsigned short* fkF     = (unsigned short*)(ws + 4194304);   // fragment-major  (2,097,152 B)
    unsigned short* num_bf  = (unsigned short*)(ws + 6291456);   // 4x8192x128 bf16 (8,388,608 B)
    float*          den_part= (float*)(ws + 14680064);           // 4x8192 f32      (131,072 B)

    float* out = (float*)d_out;

    hipLaunchKernelGGL(k_proj, dim3(768), dim3(256), 0, stream,
                       landmarks, features, Wi, bi, Wj, bj, Wk, bk, fi, fjF, fkF);
    hipLaunchKernelGGL(k_attn, dim3(1024), dim3(256), 0, stream, fi, fjF, fkF, num_bf, den_part);
    hipLaunchKernelGGL(k_out, dim3(256), dim3(256), 0, stream,
                       Wr, br, features, num_bf, den_part, out);
}

// Round 18
// 147.726 us; speedup vs baseline: 1.1617x; 1.1617x over previous
//
#include <hip/hip_runtime.h>
#include <stdint.h>

#define N_NODES 8192

typedef __attribute__((ext_vector_type(8))) short bhalf8;
typedef __attribute__((ext_vector_type(16))) float f32x16;
typedef __attribute__((ext_vector_type(4))) float f32x4;

__device__ inline unsigned short f2bf_rne(float f) {
    unsigned u = __builtin_bit_cast(unsigned, f);
    u += 0x7FFFu + ((u >> 16) & 1u);
    return (unsigned short)(u >> 16);
}

__device__ inline float bf2f(unsigned short s) {
    unsigned u = ((unsigned)s) << 16;
    return __builtin_bit_cast(float, u);
}

__device__ inline bhalf8 mk8(unsigned a, unsigned b, unsigned c, unsigned d) {
    union { unsigned u[4]; bhalf8 v; } U;
    U.u[0] = a; U.u[1] = b; U.u[2] = c; U.u[3] = d;
    return U.v;
}

// v_permlane32_swap_b32 a, b:  a = {a_lo, b_lo}, b = {a_hi, b_hi}  (rows = 32-lane halves)
__device__ inline void pl32swap(unsigned& a, unsigned& b) {
    asm("v_permlane32_swap_b32 %0, %1" : "+v"(a), "+v"(b));
}

// ---------------- k1: projections straight from f32 inputs (weights read transposed,
// coalesced, directly from global).
// fi pre-scaled by -log2e (feeds only QK^T; scores arrive exp2-ready).
// fjF layout: chunk c (64 j) x k-chunk kc (8 k) x 64 j-rows x 16 B:
//   ushort idx = (j>>6)*8192 + (k>>3)*512 + (j&63)*8 + (k&7)
// fkF layout: chunk c x j-slice s (8 j) x 128 d-rows x 16 B:
//   ushort idx = (j>>6)*8192 + ((j>>3)&7)*1024 + d*8 + (j&7)
__global__ __launch_bounds__(256) void k_proj(const float* __restrict__ landmarks,
                                              const float* __restrict__ features,
                                              const float* __restrict__ Wi,
                                              const float* __restrict__ bi,
                                              const float* __restrict__ Wj,
                                              const float* __restrict__ bj,
                                              const float* __restrict__ Wk,
                                              const float* __restrict__ bk,
                                              unsigned short* __restrict__ fi,
                                              unsigned short* __restrict__ fjF,
                                              unsigned short* __restrict__ fkF) {
    const int tid = threadIdx.x, w = tid >> 6, l = tid & 63, h = l >> 5, ln = l & 31;
    const unsigned bid = blockIdx.x;
    const int it = bid / 3, ng = bid - it * 3;
    const int i0 = it * 32;
    const int d = w * 32 + ln;
    const int row = i0 + ln;
    const float* Wsel = (ng == 0) ? Wi : ((ng == 1) ? Wj : Wk);
    const float* bsel = (ng == 0) ? bi : ((ng == 1) ? bj : bk);
    f32x16 acc = {};
#pragma unroll
    for (int s = 0; s < 17; ++s) {
        union { unsigned short us[8]; bhalf8 v; } A;
        union { unsigned short us[8]; bhalf8 v; } B;
        if (s < 16) {
            const float* fp = features + (size_t)row * 256 + s * 16 + h * 8;
            f32x4 v0 = *(const f32x4*)(fp);
            f32x4 v1 = *(const f32x4*)(fp + 4);
#pragma unroll
            for (int e = 0; e < 4; ++e) { A.us[e] = f2bf_rne(v0[e]); A.us[4 + e] = f2bf_rne(v1[e]); }
            // B: W rows (kk+3) for kk = s*16 + h*8 + e; coalesced across lanes (d varies)
#pragma unroll
            for (int e = 0; e < 8; ++e)
                B.us[e] = f2bf_rne(Wsel[(size_t)(s * 16 + h * 8 + e + 3) * 128 + d]);
        } else {
#pragma unroll
            for (int e = 0; e < 8; ++e) { A.us[e] = 0; B.us[e] = 0; }
            if (h == 0) {
                A.us[0] = f2bf_rne(landmarks[row * 3 + 0]);
                A.us[1] = f2bf_rne(landmarks[row * 3 + 1]);
                A.us[2] = f2bf_rne(landmarks[row * 3 + 2]);
                B.us[0] = f2bf_rne(Wsel[(size_t)0 * 128 + d]);
                B.us[1] = f2bf_rne(Wsel[(size_t)1 * 128 + d]);
                B.us[2] = f2bf_rne(Wsel[(size_t)2 * 128 + d]);
            }
        }
        acc = __builtin_amdgcn_mfma_f32_32x32x16_bf16(A.v, B.v, acc, 0, 0, 0);
    }
    const float bias = bsel[d];
    if (ng == 0) {
#pragma unroll
        for (int q = 0; q < 4; ++q) {
            int ib = i0 + 8 * q + 4 * h;
#pragma unroll
            for (int r = 0; r < 4; ++r)
                fi[(size_t)(ib + r) * 128 + d] =
                    f2bf_rne((acc[4 * q + r] + bias) * -1.44269504f);
        }
    } else if (ng == 1) {
#pragma unroll
        for (int q = 0; q < 4; ++q) {
            int ib = i0 + 8 * q + 4 * h;
#pragma unroll
            for (int r = 0; r < 4; ++r) {
                int j = ib + r;
                fjF[(size_t)(j >> 6) * 8192 + (d >> 3) * 512 + (j & 63) * 8 + (d & 7)] =
                    f2bf_rne(acc[4 * q + r] + bias);
            }
        }
    } else {
#pragma unroll
        for (int q = 0; q < 4; ++q) {
            int ib = i0 + 8 * q + 4 * h;
            ushort4 pk;
            pk.x = f2bf_rne(acc[4 * q + 0] + bias);
            pk.y = f2bf_rne(acc[4 * q + 1] + bias);
            pk.z = f2bf_rne(acc[4 * q + 2] + bias);
            pk.w = f2bf_rne(acc[4 * q + 3] + bias);
            *(ushort4*)(fkF + (size_t)(ib >> 6) * 8192 + ((ib >> 3) & 7) * 1024 + d * 8 + 4 * h) = pk;
        }
    }
}

// ---------------- k2: barrier-free streaming (R16 main loop, reduced peak live regs) ----
// Register-shave probe: fj prefetch depth 8->4. fjc[k] = chunk_base + k*1024 (k=0..7);
// fragments 0-3 of the NEXT chunk are prefetched (cross-iteration live), fragments 4-7
// of the CURRENT chunk load just-in-time at loop top and die after QK -> allocator can
// reuse them for p[]/fb, cutting peak live below the 160-reg 3-wave boundary
// (R16: 168 total -> 2 waves; R17 proved 112 total -> 3 waves, fine granule).
// Numerics identical to R16 (same op order). da split 4->2 (-2 regs).
__global__ __launch_bounds__(256, 2) void k_attn(const unsigned short* __restrict__ fi,
                                                 const unsigned short* __restrict__ fjF,
                                                 const unsigned short* __restrict__ fkF,
                                                 unsigned short* __restrict__ num_bf,
                                                 float* __restrict__ den_part) {
    __shared__ __align__(16) char smem[36864];   // epilogue reduce buffer only

    const int tid = threadIdx.x;
    const int w = tid >> 6, l = tid & 63, h = l >> 5, ln = l & 31;
    const int ih = w >> 1, jh = w & 1;
    const unsigned b = blockIdx.x;             // 512 blocks; xcd = b & 7 (round-robin)
    const int xcd = b & 7;
    const int jq = xcd >> 1;                   // one jq per XCD-pair (L2 locality, R4-proven)
    const int rt = (int)(b >> 3) + ((xcd & 1) << 6);
    const int i0 = rt * 64;

    // hoist fi B-fragments for this wave's 32-i block (32 VGPRs), reused across all j
    bhalf8 bfi[8];
#pragma unroll
    for (int s = 0; s < 8; ++s)
        bfi[s] = *(const bhalf8*)(fi + (size_t)(i0 + ih * 32 + ln) * 128 + s * 16 + h * 8);

    f32x16 acc[4] = {};   // numT partials: [d-tile 0..3][wave's 32 i], over wave's jh half
    float da[2] = {};     // denom partial accumulators

    // per-lane fragment base pointers (ushort units); chunk stride = 8192 ushorts (16 KB)
    const unsigned short* fjp = fjF + (size_t)(jq * 32) * 8192 + (jh * 32 + ln) * 8 + h * 512;
    const unsigned short* fkp = fkF + (size_t)(jq * 32) * 8192 + (jh * 4 + h) * 1024 + ln * 8;

    bhalf8 fjc[8];          // [0..3]: prefetched (next-chunk), [4..7]: JIT (current-chunk)
    bhalf8 fkA[4], fkB[4];  // PV fk fragments of current chunk

    auto LOADFJ_LO = [&](const unsigned short* p) {
#pragma unroll
        for (int k = 0; k < 4; ++k)
            fjc[k] = *(const bhalf8*)(p + k * 1024);
    };
    auto LOADFJ_HI = [&](const unsigned short* p) {
#pragma unroll
        for (int k = 4; k < 8; ++k)
            fjc[k] = *(const bhalf8*)(p + k * 1024);
    };
    auto LOADFK = [&](const unsigned short* p) {
#pragma unroll
        for (int m4 = 0; m4 < 4; ++m4) {
            fkA[m4] = *(const bhalf8*)(p + m4 * 256);
            fkB[m4] = *(const bhalf8*)(p + 2048 + m4 * 256);
        }
    };

    LOADFJ_LO(fjp);
    LOADFK(fkp);
#pragma unroll 1
    for (int mt = 0; mt < 32; ++mt) {
        // JIT-load current chunk's second-half fj fragments (land mid-QK)
        LOADFJ_HI(fjp);
        // QK: scores arrive pre-scaled by -log2e (fi scaled at k1) — exp2-ready.
        // Same accumulation order as R16: sa gets k=0,2,4,6; sb gets k=1,3,5,7.
        f32x16 sa = {}, sb = {};
        __builtin_amdgcn_s_setprio(1);
        sa = __builtin_amdgcn_mfma_f32_32x32x16_bf16(fjc[0], bfi[0], sa, 0, 0, 0);
        sb = __builtin_amdgcn_mfma_f32_32x32x16_bf16(fjc[1], bfi[1], sb, 0, 0, 0);
        sa = __builtin_amdgcn_mfma_f32_32x32x16_bf16(fjc[2], bfi[2], sa, 0, 0, 0);
        sb = __builtin_amdgcn_mfma_f32_32x32x16_bf16(fjc[3], bfi[3], sb, 0, 0, 0);
        sa = __builtin_amdgcn_mfma_f32_32x32x16_bf16(fjc[4], bfi[4], sa, 0, 0, 0);
        sb = __builtin_amdgcn_mfma_f32_32x32x16_bf16(fjc[5], bfi[5], sb, 0, 0, 0);
        sa = __builtin_amdgcn_mfma_f32_32x32x16_bf16(fjc[6], bfi[6], sa, 0, 0, 0);
        sb = __builtin_amdgcn_mfma_f32_32x32x16_bf16(fjc[7], bfi[7], sb, 0, 0, 0);
        __builtin_amdgcn_s_setprio(0);
        // prefetch next chunk's first-half fj (fjc[0..3] dead after QK above)
        fjp += 8192;
        LOADFJ_LO(fjp);
        // sigmoid + denom + pack: x = rcp(1 + exp2(s')) — 16 independent chains
        unsigned p[8];
#pragma unroll
        for (int q = 0; q < 8; ++q) {
            float x0 = __builtin_amdgcn_rcpf(1.f + __builtin_amdgcn_exp2f(sa[2 * q] + sb[2 * q]));
            float x1 = __builtin_amdgcn_rcpf(1.f + __builtin_amdgcn_exp2f(sa[2 * q + 1] + sb[2 * q + 1]));
            da[q & 1] += x0 + x1;
            p[q] = __builtin_amdgcn_perm(__builtin_bit_cast(unsigned, x1),
                                         __builtin_bit_cast(unsigned, x0), 0x07060302u);
        }
        unsigned w0 = p[0], w2 = p[2]; pl32swap(w0, w2);
        unsigned w1 = p[1], w3 = p[3]; pl32swap(w1, w3);
        bhalf8 fb0 = mk8(w0, w1, w2, w3);
        unsigned w4 = p[4], w6 = p[6]; pl32swap(w4, w6);
        unsigned w5 = p[5], w7 = p[7]; pl32swap(w5, w7);
        bhalf8 fb1 = mk8(w4, w5, w6, w7);
        // PV: numT[d][i] += fk[d][j-slice] * P^T[j-slice][i]
        __builtin_amdgcn_s_setprio(1);
#pragma unroll
        for (int m4 = 0; m4 < 4; ++m4)
            acc[m4] = __builtin_amdgcn_mfma_f32_32x32x16_bf16(fkA[m4], fb0, acc[m4], 0, 0, 0);
#pragma unroll
        for (int m4 = 0; m4 < 4; ++m4)
            acc[m4] = __builtin_amdgcn_mfma_f32_32x32x16_bf16(fkB[m4], fb1, acc[m4], 0, 0, 0);
        __builtin_amdgcn_s_setprio(0);
        // prefetch next chunk's fk
        fkp += 8192;
        LOADFK(fkp);
    }

    // denom: combine partials, fold lane l <-> l^32 (h halves), stash per wave
    float dacc = da[0] + da[1];
    dacc += __shfl_xor(dacc, 32, 64);
    float* denb = (float*)(smem + 34816);   // 128 floats, after the 34,816 B reduce buf
    if (h == 0) denb[w * 32 + ln] = dacc;

    // num reduce: jh=0 waves write [64 i][128 d] (pad 132), jh=1 waves add
    float* buf = (float*)smem;
    __syncthreads();   // first barrier (no LDS used before)
    if (jh == 0) {
#pragma unroll
        for (int m4 = 0; m4 < 4; ++m4)
#pragma unroll
            for (int q = 0; q < 4; ++q) {
                f32x4 v = {acc[m4][4 * q + 0], acc[m4][4 * q + 1],
                           acc[m4][4 * q + 2], acc[m4][4 * q + 3]};
                *(f32x4*)(buf + (ih * 32 + ln) * 132 + m4 * 32 + 8 * q + 4 * h) = v;
            }
    }
    __syncthreads();
    if (jh == 1) {
#pragma unroll
        for (int m4 = 0; m4 < 4; ++m4)
#pragma unroll
            for (int q = 0; q < 4; ++q) {
                float* p4 = buf + (ih * 32 + ln) * 132 + m4 * 32 + 8 * q + 4 * h;
                f32x4 old = *(f32x4*)p4;
                f32x4 v = {acc[m4][4 * q + 0], acc[m4][4 * q + 1],
                           acc[m4][4 * q + 2], acc[m4][4 * q + 3]};
                *(f32x4*)p4 = old + v;
            }
    }
    __syncthreads();
#pragma unroll
    for (int e = 0; e < 8; ++e) {
        int v = e * 256 + tid;                 // 2048 float4-groups = 64 i x 32
        int iloc = v >> 5, d4 = (v & 31) * 4;
        f32x4 s4 = *(const f32x4*)(buf + iloc * 132 + d4);
        ushort4 pk;
        pk.x = f2bf_rne(s4.x);
        pk.y = f2bf_rne(s4.y);
        pk.z = f2bf_rne(s4.z);
        pk.w = f2bf_rne(s4.w);
        *(ushort4*)(num_bf + ((size_t)jq * N_NODES + i0 + iloc) * 128 + d4) = pk;
    }
    if (tid < 64) {
        den_part[(size_t)jq * N_NODES + i0 + tid] =
            denb[(tid >> 5) * 64 + (tid & 31)] + denb[(tid >> 5) * 64 + 32 + (tid & 31)];
    }
}

// ---------------- k3: t = (sum num)/(sum den); out = t @ Wr + br + features ----------------
// num partials read as bf16 (half the bytes), accumulated in f32; Wr streamed directly
// from global (coalesced, L2-cached).
__global__ __launch_bounds__(256) void k_out(const float* __restrict__ Wr,
                                             const float* __restrict__ br,
                                             const float* __restrict__ features,
                                             const unsigned short* __restrict__ num_bf,
                                             const float* __restrict__ den_part,
                                             float* __restrict__ out) {
    __shared__ __align__(16) char smem[8192];   // t tile [32 i][256 B] swizzled
    char* const tb = smem;
    const int tid = threadIdx.x, w = tid >> 6, l = tid & 63, h = l >> 5, ln = l & 31;
    const int i0 = blockIdx.x * 32;
    // combine num/den partials -> t tile (bf16)
    {
        int i = tid >> 3, dseg = (tid & 7) * 16;
        f32x4 s[4] = {};
        float ds = 0.f;
#pragma unroll
        for (int q = 0; q < 4; ++q) {
            const unsigned short* np = num_bf + ((size_t)(q * N_NODES + i0 + i)) * 128 + dseg;
            bhalf8 b0 = *(const bhalf8*)(np);
            bhalf8 b1 = *(const bhalf8*)(np + 8);
#pragma unroll
            for (int k = 0; k < 8; ++k)
                s[k >> 2][k & 3] += bf2f((unsigned short)b0[k]);
#pragma unroll
            for (int k = 0; k < 8; ++k)
                s[2 + (k >> 2)][k & 3] += bf2f((unsigned short)b1[k]);
            ds += den_part[(size_t)q * N_NODES + i0 + i];
        }
        float inv = 1.0f / ds;
#pragma unroll
        for (int cc = 0; cc < 2; ++cc) {
            union { unsigned u[4]; bhalf8 v; } U;
#pragma unroll
            for (int m = 0; m < 4; ++m) {
                int e0 = cc * 8 + 2 * m;
                unsigned lo = f2bf_rne(s[e0 >> 2][e0 & 3] * inv);
                unsigned hi = f2bf_rne(s[(e0 + 1) >> 2][(e0 + 1) & 3] * inv);
                U.u[m] = lo | (hi << 16);
            }
            int slot = ((tid & 7) * 2 + cc) ^ (i & 15);
            *(bhalf8*)(tb + i * 256 + slot * 16) = U.v;
        }
    }
    __syncthreads();
    f32x16 acc[2] = {};
    const int cc0 = w * 64 + ln;   // this lane's output column base (nt adds 32)
#pragma unroll
    for (int s = 0; s < 8; ++s) {
        int ca = (s * 2 + h) ^ (ln & 15);
        bhalf8 af = *(const bhalf8*)(tb + ln * 256 + ca * 16);
#pragma unroll
        for (int nt = 0; nt < 2; ++nt) {
            int cc = cc0 + nt * 32;
            union { unsigned short us[8]; bhalf8 v; } B;
#pragma unroll
            for (int e = 0; e < 8; ++e)
                B.us[e] = f2bf_rne(Wr[(size_t)((s * 2 + h) * 8 + e) * 256 + cc]);
            acc[nt] = __builtin_amdgcn_mfma_f32_32x32x16_bf16(af, B.v, acc[nt], 0, 0, 0);
        }
    }
#pragma unroll
    for (int nt = 0; nt < 2; ++nt) {
        int cc = cc0 + nt * 32;
        float bias = br[cc];
#pragma unroll
        for (int q = 0; q < 4; ++q) {
#pragma unroll
            for (int r = 0; r < 4; ++r) {
                int i = i0 + 8 * q + 4 * h + r;
                out[(size_t)i * 256 + cc] = acc[nt][4 * q + r] + bias + features[(size_t)i * 256 + cc];
            }
        }
    }
}

extern "C" void kernel_launch(void* const* d_in, const int* in_sizes, int n_in,
                              void* d_out, int out_size, void* d_ws, size_t ws_size,
                              hipStream_t stream) {
    const float* landmarks = (const float*)d_in[0];
    const float* features  = (const float*)d_in[1];
    const float* Wi = (const float*)d_in[2];
    const float* bi = (const float*)d_in[3];
    const float* Wj = (const float*)d_in[4];
    const float* bj = (const float*)d_in[5];
    const float* Wk = (const float*)d_in[6];
    const float* bk = (const float*)d_in[7];
    const float* Wr = (const float*)d_in[8];
    const float* br = (const float*)d_in[9];

    char* ws = (char*)d_ws;
    unsigned short* fi      = (unsigned short*)(ws + 0);         // 8192x128 bf16   (2,097,152 B)
    unsigned short* fjF     = (unsigned short*)(ws + 2097152);   // fragment-major  (2,097,152 B)
    unsigned short* fkF     = (unsigned short*)(ws + 4194304);   // fragment-major  (2,097,152 B)
    unsigned short* num_bf  = (unsigned short*)(ws + 6291456);   // 4x8192x128 bf16 (8,388,608 B)
    float*          den_part= (float*)(ws + 14680064);           // 4x8192 f32      (131,072 B)

    float* out = (float*)d_out;

    hipLaunchKernelGGL(k_proj, dim3(768), dim3(256), 0, stream,
                       landmarks, features, Wi, bi, Wj, bj, Wk, bk, fi, fjF, fkF);
    hipLaunchKernelGGL(k_attn, dim3(512), dim3(256), 0, stream, fi, fjF, fkF, num_bf, den_part);
    hipLaunchKernelGGL(k_out, dim3(256), dim3(256), 0, stream,
                       Wr, br, features, num_bf, den_part, out);
}